// Round 2
// baseline (248.613 us; speedup 1.0000x reference)
//
#include <hip/hip_runtime.h>
#include <hip/hip_bf16.h>

// ConvSelfAttn: B=8, H=W=64 (N=4096), C=64, d=C/8=8 — ALL I/O IS FP32 (per reference).
// q = x@wq+bq [B,N,8]; k = x@wk+bk [B,N,8]; v = x@wv+bv [B,N,64]
// out = softmax(q k^T) @ v * gamma + x
//
// proj kernels write fp16 Q/K/V to ws; flash-attention kernel with
// mfma_f32_16x16x32_f16 (d=8 zero-padded in K), online softmax, P via LDS
// round-trip (D-layout -> A-layout, per m120), V transposed in LDS (stride 72
// breaks bank aliasing). Output fp32 with residual + gamma fused.

#define BB 8
#define NN 4096
#define CC 64

typedef _Float16 f16;
typedef _Float16 half8 __attribute__((ext_vector_type(8)));
typedef float floatx4 __attribute__((ext_vector_type(4)));

#define KT 64   // keys per tile
#define QB 64   // queries per block (4 waves x 16)
#define VS 72   // padded LDS row stride in halfs (64 + 8)

// ---------------- projection: V ----------------
__global__ __launch_bounds__(256) void proj_v_kernel(
    const float* __restrict__ x,    // [B*N, 64]
    const float* __restrict__ wv,   // [64,64] row-major [cin][cout]
    const float* __restrict__ bv,   // [64]
    f16* __restrict__ Vh)           // [B*N, 64]
{
    __shared__ float w_s[64 * 64];
    __shared__ float x_s[32][65];
    const int tid = threadIdx.x;
    for (int i = tid; i < 1024; i += 256) {
        *(float4*)(&w_s[i * 4]) = *(const float4*)(wv + i * 4);
    }
    const long pix0 = (long)blockIdx.x * 32;
    for (int i = tid; i < 512; i += 256) {
        int p = i >> 4, c4 = (i & 15) * 4;
        float4 xv = *(const float4*)(x + (pix0 + p) * 64 + c4);
        x_s[p][c4 + 0] = xv.x; x_s[p][c4 + 1] = xv.y;
        x_s[p][c4 + 2] = xv.z; x_s[p][c4 + 3] = xv.w;
    }
    __syncthreads();
    const int p  = tid >> 3;        // 0..31
    const int c0 = (tid & 7) * 8;   // 0..56
    float acc[8];
#pragma unroll
    for (int u = 0; u < 8; ++u) acc[u] = bv[c0 + u];
    for (int i = 0; i < 64; ++i) {
        float xv = x_s[p][i];
        const float* wr = &w_s[i * 64 + c0];
#pragma unroll
        for (int u = 0; u < 8; ++u) acc[u] = fmaf(xv, wr[u], acc[u]);
    }
    f16* outp = Vh + (pix0 + p) * 64 + c0;
#pragma unroll
    for (int u = 0; u < 8; ++u) outp[u] = (f16)acc[u];
}

// ---------------- projection: Q and K ----------------
__global__ __launch_bounds__(256) void proj_qk_kernel(
    const float* __restrict__ x,
    const float* __restrict__ wq, const float* __restrict__ bq,
    const float* __restrict__ wk, const float* __restrict__ bk,
    f16* __restrict__ Qh, f16* __restrict__ Kh)   // each [B*N, 8]
{
    __shared__ float wq_s[64 * 8];
    __shared__ float wk_s[64 * 8];
    __shared__ float x_s[16][65];
    const int tid = threadIdx.x;
    for (int i = tid; i < 512; i += 256) {
        wq_s[i] = wq[i];
        wk_s[i] = wk[i];
    }
    const long pix0 = (long)blockIdx.x * 16;
    for (int i = tid; i < 256; i += 256) {
        int p = i >> 4, c4 = (i & 15) * 4;
        float4 xv = *(const float4*)(x + (pix0 + p) * 64 + c4);
        x_s[p][c4 + 0] = xv.x; x_s[p][c4 + 1] = xv.y;
        x_s[p][c4 + 2] = xv.z; x_s[p][c4 + 3] = xv.w;
    }
    __syncthreads();
    const int p = tid >> 4, o = tid & 15;
    const int cc = o & 7;
    const float* w_s = (o < 8) ? wq_s : wk_s;
    float acc = (o < 8) ? bq[cc] : bk[cc];
    for (int i = 0; i < 64; ++i) acc = fmaf(x_s[p][i], w_s[i * 8 + cc], acc);
    f16* dst = (o < 8) ? Qh : Kh;
    dst[(pix0 + p) * 8 + cc] = (f16)acc;
}

// ---------------- flash attention ----------------
// grid = B * (N/QB) = 8*64 = 512 blocks, 256 threads (4 waves x 16-query tile)
__global__ __launch_bounds__(256) void attn_kernel(
    const f16* __restrict__ Qh, const f16* __restrict__ Kh,
    const f16* __restrict__ Vh,
    const float* __restrict__ x,
    const float* __restrict__ gptr,
    float* __restrict__ out)
{
    __shared__ alignas(16) f16 Kt[KT * 8];        // [key][8]    1 KiB
    __shared__ alignas(16) f16 Vt[64 * VS];       // [ch][key]   9 KiB (padded)
    __shared__ alignas(16) f16 Pt[4][16 * VS];    // per-wave P  9 KiB (padded)

    const int tid  = threadIdx.x;
    const int wave = tid >> 6;
    const int lane = tid & 63;
    const int quad = lane >> 4;
    const int n16  = lane & 15;

    const int b  = blockIdx.x >> 6;    // batch
    const int qb = blockIdx.x & 63;    // query tile within batch
    const int qbase = qb * QB;
    const size_t bN = (size_t)b * NN;

    // Q A-fragment: A[m=lane&15][k=quad*8+j]; d=8 so only quad 0 is real.
    half8 aq = {0, 0, 0, 0, 0, 0, 0, 0};
    if (quad == 0) {
        const f16* qp = Qh + (bN + qbase + wave * 16 + n16) * 8;
        aq = *(const half8*)qp;
    }

    floatx4 oacc[4];
#pragma unroll
    for (int ct = 0; ct < 4; ++ct) oacc[ct] = (floatx4){0.f, 0.f, 0.f, 0.f};
    float m_run[4], l_run[4];
#pragma unroll
    for (int r = 0; r < 4; ++r) { m_run[r] = -1e30f; l_run[r] = 0.f; }

    const floatx4 zero4 = {0.f, 0.f, 0.f, 0.f};

    for (int kt = 0; kt < NN / KT; ++kt) {
        __syncthreads();
        // stage K tile: 64 keys x 8 halfs (16B per key)
        if (tid < 64) {
            *(float4*)(&Kt[tid * 8]) =
                *(const float4*)(Kh + (bN + (size_t)kt * KT + tid) * 8);
        }
        // stage V tile transposed: Vt[ch][key]
        {
            const int key = tid >> 2, cg = tid & 3;
            const f16* vp = Vh + (bN + (size_t)kt * KT + key) * 64 + cg * 16;
            half8 va = *(const half8*)vp;
            half8 vb = *(const half8*)(vp + 8);
#pragma unroll
            for (int u = 0; u < 8; ++u) {
                Vt[(cg * 16 + u) * VS + key]     = va[u];
                Vt[(cg * 16 + 8 + u) * VS + key] = vb[u];
            }
        }
        __syncthreads();

        // S = Q K^T : 4 MFMAs over 16-key subtiles.
        // B[k=quad*8+j][n=lane&15] = K[key=n][ch=k]; zero for k>=8.
        floatx4 sf[4];
#pragma unroll
        for (int t = 0; t < 4; ++t) {
            half8 bk = {0, 0, 0, 0, 0, 0, 0, 0};
            if (quad == 0) bk = *(const half8*)(&Kt[(t * 16 + n16) * 8]);
            sf[t] = __builtin_amdgcn_mfma_f32_16x16x32_f16(aq, bk, zero4, 0, 0, 0);
        }

        // online softmax: lane holds rows quad*4+r, col = 16*t + n16
        float alpha[4];
#pragma unroll
        for (int r = 0; r < 4; ++r) {
            float mx = fmaxf(fmaxf(sf[0][r], sf[1][r]), fmaxf(sf[2][r], sf[3][r]));
#pragma unroll
            for (int d = 1; d < 16; d <<= 1) mx = fmaxf(mx, __shfl_xor(mx, d, 64));
            float mnew = fmaxf(m_run[r], mx);
            alpha[r] = __expf(m_run[r] - mnew);
            m_run[r] = mnew;
            float rs = 0.f;
#pragma unroll
            for (int t = 0; t < 4; ++t) {
                float pv = __expf(sf[t][r] - mnew);
                sf[t][r] = pv;
                rs += pv;
            }
#pragma unroll
            for (int d = 1; d < 16; d <<= 1) rs += __shfl_xor(rs, d, 64);
            l_run[r] = l_run[r] * alpha[r] + rs;
        }
#pragma unroll
        for (int ct = 0; ct < 4; ++ct)
#pragma unroll
            for (int r = 0; r < 4; ++r) oacc[ct][r] *= alpha[r];

        // P: D-layout -> LDS -> A-layout (per-wave buffer, no barrier needed)
        f16* Pw = &Pt[wave][0];
#pragma unroll
        for (int t = 0; t < 4; ++t)
#pragma unroll
            for (int r = 0; r < 4; ++r)
                Pw[(quad * 4 + r) * VS + t * 16 + n16] = (f16)sf[t][r];
        __asm__ volatile("s_waitcnt lgkmcnt(0)" ::: "memory");

        // O += P V : 2 key-halves x 4 channel tiles
#pragma unroll
        for (int h = 0; h < 2; ++h) {
            half8 ap = *(const half8*)(&Pw[n16 * VS + h * 32 + quad * 8]);
#pragma unroll
            for (int ct = 0; ct < 4; ++ct) {
                half8 bv = *(const half8*)(&Vt[(ct * 16 + n16) * VS + h * 32 + quad * 8]);
                oacc[ct] = __builtin_amdgcn_mfma_f32_16x16x32_f16(ap, bv, oacc[ct], 0, 0, 0);
            }
        }
    }

    // epilogue: normalize, gamma, residual
    const float g = gptr[0];
#pragma unroll
    for (int ct = 0; ct < 4; ++ct) {
#pragma unroll
        for (int r = 0; r < 4; ++r) {
            int q  = qbase + wave * 16 + quad * 4 + r;
            int ch = ct * 16 + n16;
            size_t idx = (bN + q) * (size_t)CC + ch;
            float val = (oacc[ct][r] / l_run[r]) * g + x[idx];
            out[idx] = val;
        }
    }
}

extern "C" void kernel_launch(void* const* d_in, const int* in_sizes, int n_in,
                              void* d_out, int out_size, void* d_ws, size_t ws_size,
                              hipStream_t stream) {
    const float* x     = (const float*)d_in[0];
    const float* wq    = (const float*)d_in[1];
    const float* bq    = (const float*)d_in[2];
    const float* wk    = (const float*)d_in[3];
    const float* bk    = (const float*)d_in[4];
    const float* wv    = (const float*)d_in[5];
    const float* bv    = (const float*)d_in[6];
    const float* gamma = (const float*)d_in[7];
    float* out = (float*)d_out;

    // ws layout (fp16): Q [B*N,8] | K [B*N,8] | V [B*N,64]  -> 5 MiB total
    f16* Qh = (f16*)d_ws;
    f16* Kh = Qh + (size_t)BB * NN * 8;
    f16* Vh = Kh + (size_t)BB * NN * 8;

    proj_v_kernel<<<(BB * NN) / 32, 256, 0, stream>>>(x, wv, bv, Vh);
    proj_qk_kernel<<<(BB * NN) / 16, 256, 0, stream>>>(x, wq, bq, wk, bk, Qh, Kh);
    attn_kernel<<<BB * (NN / QB), 256, 0, stream>>>(Qh, Kh, Vh, x, gamma, out);
}

// Round 3
// 206.787 us; speedup vs baseline: 1.2023x; 1.2023x over previous
//
#include <hip/hip_runtime.h>
#include <hip/hip_bf16.h>

// ConvSelfAttn: B=8, N=4096, C=64, d=8. FP32 I/O.
// R3: S^T formulation (K@Q^T), barrier-free K-loop, key-split-2 (8 waves/block),
// V pre-transposed -> direct 16B global A-frag loads, conflict-free per-wave
// P round-trip, single fused MFMA projection kernel.

#define BB 8
#define NN 4096
#define CC 64
#define PSTRIDE 72   // halfs per P-buffer row (16*9B rows -> conflict-free b128)

typedef _Float16 f16;
typedef _Float16 half8 __attribute__((ext_vector_type(8)));
typedef _Float16 half4 __attribute__((ext_vector_type(4)));
typedef float floatx4 __attribute__((ext_vector_type(4)));

// ---------------- fused projection (MFMA): Q,K,V^T ----------------
// grid 512 x 256 (4 waves x 16 pixels). Per wave: x[16x64] @ W[64x80].
__global__ __launch_bounds__(256) void proj_all_kernel(
    const float* __restrict__ x,
    const float* __restrict__ wq, const float* __restrict__ bq,
    const float* __restrict__ wk, const float* __restrict__ bk,
    const float* __restrict__ wv, const float* __restrict__ bv,
    f16* __restrict__ Qh, f16* __restrict__ Kh, f16* __restrict__ VT)
{
    const int tid  = threadIdx.x;
    const int wave = tid >> 6, lane = tid & 63;
    const int quad = lane >> 4, n16 = lane & 15;
    const long p0 = (long)blockIdx.x * 64 + wave * 16;

    // W B-frags: B[k=cin][n=cout], k = kh*32 + quad*8 + j. ct 0..3 = V, ct 4 = Q|K.
    half8 bw[5][2];
    float biasv[5];
#pragma unroll
    for (int kh = 0; kh < 2; ++kh) {
        const int cin0 = kh * 32 + quad * 8;
#pragma unroll
        for (int ct = 0; ct < 4; ++ct)
#pragma unroll
            for (int j = 0; j < 8; ++j)
                bw[ct][kh][j] = (f16)wv[(cin0 + j) * 64 + ct * 16 + n16];
        const float* wqk = (n16 < 8) ? (wq + n16) : (wk + (n16 - 8));
#pragma unroll
        for (int j = 0; j < 8; ++j)
            bw[4][kh][j] = (f16)wqk[(cin0 + j) * 8];
    }
#pragma unroll
    for (int ct = 0; ct < 4; ++ct) biasv[ct] = bv[ct * 16 + n16];
    biasv[4] = (n16 < 8) ? bq[n16] : bk[n16 - 8];

    // x A-frags: A[m=pixel][k=cin], m = n16, k = kh*32 + quad*8 + j
    half8 ax[2];
#pragma unroll
    for (int kh = 0; kh < 2; ++kh) {
        const float* xp = x + (p0 + n16) * 64 + kh * 32 + quad * 8;
        float4 x1 = *(const float4*)xp;
        float4 x2 = *(const float4*)(xp + 4);
        ax[kh][0] = (f16)x1.x; ax[kh][1] = (f16)x1.y;
        ax[kh][2] = (f16)x1.z; ax[kh][3] = (f16)x1.w;
        ax[kh][4] = (f16)x2.x; ax[kh][5] = (f16)x2.y;
        ax[kh][6] = (f16)x2.z; ax[kh][7] = (f16)x2.w;
    }

    const int b   = (int)(p0 >> 12);
    const int nn0 = (int)(p0 & 4095);
#pragma unroll
    for (int ct = 0; ct < 5; ++ct) {
        floatx4 acc = {biasv[ct], biasv[ct], biasv[ct], biasv[ct]};
        acc = __builtin_amdgcn_mfma_f32_16x16x32_f16(ax[0], bw[ct][0], acc, 0, 0, 0);
        acc = __builtin_amdgcn_mfma_f32_16x16x32_f16(ax[1], bw[ct][1], acc, 0, 0, 0);
        if (ct < 4) {
            // D[m=pixel=quad*4+r][n=ch_local=n16] -> VT[b*64+ch][pixel], 8B packed
            half4 pk;
#pragma unroll
            for (int r = 0; r < 4; ++r) pk[r] = (f16)acc[r];
            *(half4*)(VT + ((size_t)(b * 64 + ct * 16 + n16)) * NN + nn0 + quad * 4) = pk;
        } else {
            f16* dst = (n16 < 8) ? (Qh + (p0 + quad * 4) * 8 + n16)
                                 : (Kh + (p0 + quad * 4) * 8 + (n16 - 8));
#pragma unroll
            for (int r = 0; r < 4; ++r) dst[r * 8] = (f16)acc[r];
        }
    }
}

// ---------------- flash attention, S^T form ----------------
// grid 512 x 512 (8 waves: qsub = wave&3, khalf = wave>>2; 16 q/wave, 2048 keys/wave)
__global__ __launch_bounds__(512, 4) void attn_kernel(
    const f16* __restrict__ Qh, const f16* __restrict__ Kh,
    const f16* __restrict__ VT,
    const float* __restrict__ x, const float* __restrict__ gptr,
    float* __restrict__ out)
{
    __shared__ alignas(16) f16   Pbuf[8 * 16 * PSTRIDE];   // 18.4 KB
    __shared__ alignas(16) float Obuf[4 * 64 * 20];        // 20.5 KB
    __shared__ float MLbuf[4 * 16 * 2];

    const int tid  = threadIdx.x;
    const int wave = tid >> 6, lane = tid & 63;
    const int quad = lane >> 4, n16 = lane & 15;
    const int qsub = wave & 3, khalf = wave >> 2;

    const int b  = blockIdx.x >> 6;
    const int qb = blockIdx.x & 63;
    const int q  = qb * 64 + qsub * 16 + n16;   // this lane's query
    const size_t bN = (size_t)b * NN;

    // Q B-frag: B[k=ch][n=query], quad0 only (d=8)
    half8 bq8;
#pragma unroll
    for (int j = 0; j < 8; ++j) bq8[j] = (f16)0.f;
    if (quad == 0) bq8 = *(const half8*)(Qh + (bN + q) * 8);

    floatx4 oacc[4];
#pragma unroll
    for (int ct = 0; ct < 4; ++ct) oacc[ct] = (floatx4){0.f, 0.f, 0.f, 0.f};
    float m_run = -1e30f, l_run = 0.f;

    const f16* kptr  = Kh + (bN + (size_t)khalf * 2048) * 8;
    const f16* vbase = VT + (size_t)b * 64 * NN + (size_t)khalf * 2048;
    const floatx4 zero4 = {0.f, 0.f, 0.f, 0.f};
    f16* Pw = Pbuf + wave * 16 * PSTRIDE;

    for (int it = 0; it < 32; ++it) {
        const int k0 = it * 64;
        // K A-frags (quad0 only): A[m=key][k=ch]
        half8 ak[4];
#pragma unroll
        for (int t = 0; t < 4; ++t)
#pragma unroll
            for (int j = 0; j < 8; ++j) ak[t][j] = (f16)0.f;
        if (quad == 0) {
#pragma unroll
            for (int t = 0; t < 4; ++t)
                ak[t] = *(const half8*)(kptr + (k0 + t * 16 + n16) * 8);
        }
        // V^T A-frags (issued early; consumed after softmax)
        half8 av[2][4];
#pragma unroll
        for (int h = 0; h < 2; ++h)
#pragma unroll
            for (int ct = 0; ct < 4; ++ct)
                av[h][ct] = *(const half8*)(vbase + (size_t)(ct * 16 + n16) * NN
                                            + k0 + h * 32 + quad * 8);

        // S^T = K Q^T: D[m=key=quad*4+r (+16t)][n=query=n16]
        floatx4 sf[4];
#pragma unroll
        for (int t = 0; t < 4; ++t)
            sf[t] = __builtin_amdgcn_mfma_f32_16x16x32_f16(ak[t], bq8, zero4, 0, 0, 0);

        // online softmax: lane holds 16 keys of query n16; reduce in-lane + lanes ^16,^32
        float mx = sf[0][0];
#pragma unroll
        for (int t = 0; t < 4; ++t)
#pragma unroll
            for (int r = 0; r < 4; ++r) mx = fmaxf(mx, sf[t][r]);
        mx = fmaxf(mx, __shfl_xor(mx, 16, 64));
        mx = fmaxf(mx, __shfl_xor(mx, 32, 64));
        const float mnew = fmaxf(m_run, mx);
        const float alpha = __expf(m_run - mnew);
        float rs = 0.f;
#pragma unroll
        for (int t = 0; t < 4; ++t)
#pragma unroll
            for (int r = 0; r < 4; ++r) {
                float pv = __expf(sf[t][r] - mnew);
                sf[t][r] = pv;
                rs += pv;
            }
        rs += __shfl_xor(rs, 16, 64);
        rs += __shfl_xor(rs, 32, 64);
        m_run = mnew;
        l_run = l_run * alpha + rs;
#pragma unroll
        for (int ct = 0; ct < 4; ++ct) oacc[ct] *= alpha;

        // P^T -> per-wave LDS (packed b64, conflict-free), read back as B-frags
#pragma unroll
        for (int t = 0; t < 4; ++t) {
            half4 pk;
#pragma unroll
            for (int r = 0; r < 4; ++r) pk[r] = (f16)sf[t][r];
            *(half4*)(Pw + n16 * PSTRIDE + t * 16 + quad * 4) = pk;
        }
        __asm__ volatile("s_waitcnt lgkmcnt(0)" ::: "memory");
        half8 bp0 = *(const half8*)(Pw + n16 * PSTRIDE + quad * 8);
        half8 bp1 = *(const half8*)(Pw + n16 * PSTRIDE + 32 + quad * 8);

        // O^T += V^T P^T
#pragma unroll
        for (int ct = 0; ct < 4; ++ct)
            oacc[ct] = __builtin_amdgcn_mfma_f32_16x16x32_f16(av[0][ct], bp0, oacc[ct], 0, 0, 0);
#pragma unroll
        for (int ct = 0; ct < 4; ++ct)
            oacc[ct] = __builtin_amdgcn_mfma_f32_16x16x32_f16(av[1][ct], bp1, oacc[ct], 0, 0, 0);
    }

    // merge key-halves: upper waves publish state, lower waves combine + epilogue
    __syncthreads();
    if (khalf == 1) {
        if (quad == 0) {
            MLbuf[((wave - 4) * 16 + n16) * 2 + 0] = m_run;
            MLbuf[((wave - 4) * 16 + n16) * 2 + 1] = l_run;
        }
        float* ob = Obuf + ((wave - 4) * 64 + lane) * 20;
#pragma unroll
        for (int ct = 0; ct < 4; ++ct) *(floatx4*)(ob + ct * 4) = oacc[ct];
    }
    __syncthreads();
    if (khalf == 0) {
        const float m2 = MLbuf[(wave * 16 + n16) * 2 + 0];
        const float l2 = MLbuf[(wave * 16 + n16) * 2 + 1];
        const float mf = fmaxf(m_run, m2);
        const float a1 = __expf(m_run - mf);
        const float a2 = __expf(m2 - mf);
        const float lf = l_run * a1 + l2 * a2;
        const float scale = gptr[0] / lf;
        const float* ob = Obuf + (wave * 64 + lane) * 20;
#pragma unroll
        for (int ct = 0; ct < 4; ++ct) {
            floatx4 o2 = *(const floatx4*)(ob + ct * 4);
            const size_t idx = (bN + q) * CC + ct * 16 + quad * 4;
            float4 xr = *(const float4*)(x + idx);
            float4 res;
            res.x = (oacc[ct][0] * a1 + o2[0] * a2) * scale + xr.x;
            res.y = (oacc[ct][1] * a1 + o2[1] * a2) * scale + xr.y;
            res.z = (oacc[ct][2] * a1 + o2[2] * a2) * scale + xr.z;
            res.w = (oacc[ct][3] * a1 + o2[3] * a2) * scale + xr.w;
            *(float4*)(out + idx) = res;
        }
    }
}

extern "C" void kernel_launch(void* const* d_in, const int* in_sizes, int n_in,
                              void* d_out, int out_size, void* d_ws, size_t ws_size,
                              hipStream_t stream) {
    const float* x     = (const float*)d_in[0];
    const float* wq    = (const float*)d_in[1];
    const float* bq    = (const float*)d_in[2];
    const float* wk    = (const float*)d_in[3];
    const float* bk    = (const float*)d_in[4];
    const float* wv    = (const float*)d_in[5];
    const float* bv    = (const float*)d_in[6];
    const float* gamma = (const float*)d_in[7];
    float* out = (float*)d_out;

    // ws (fp16): Q [B*N,8] | K [B*N,8] | VT [B,64,N]
    f16* Qh = (f16*)d_ws;
    f16* Kh = Qh + (size_t)BB * NN * 8;
    f16* VT = Kh + (size_t)BB * NN * 8;

    proj_all_kernel<<<512, 256, 0, stream>>>(x, wq, bq, wk, bk, wv, bv, Qh, Kh, VT);
    attn_kernel<<<512, 512, 0, stream>>>(Qh, Kh, VT, x, gamma, out);
}